// Round 6
// baseline (510.131 us; speedup 1.0000x reference)
//
#include <hip/hip_runtime.h>
#include <math.h>

// ---------------------------------------------------------------------------
// MS-SSIM + MSE loss, (16,3,512,512) f32, 5 pyramid levels.
// R6: wave-private column streaming. Each WAVE owns 64 output columns and a
// private 3-row LDS ring (74 cols w/ halo). No __syncthreads anywhere in the
// row loop — only a per-row wave fence (s_waitcnt lgkmcnt(0)+sched_barrier).
// Global loads issued 2 rows ahead (register pipeline) -> LDS write 1 row
// ahead -> H-conv (static ds offsets) -> 55-reg transposed-FIR V-pass ->
// SSIM/CS emit. MSE (L0) + 2x2 avgpool fused. Per-wave partials, final
// 1-block f64 reduce. No atomics.
// ---------------------------------------------------------------------------

#define NPLANES 48

struct GaussW { float g[11]; };

// ws float offsets: pyramids unchanged; per-WAVE partial areas
#define PYR2_OFF  4177920
#define P_L0      8355840   // 6144 pairs
#define P_L1      8368128   // 1536 pairs
#define P_L2      8371200   // 384 pairs
#define P_L3      8371968   // 96 pairs
#define P_L4      8372160   // 48 pairs
#define P_MSE     8372256   // 6144 singles

#define C1F 1.0e-4f
#define C2F 9.0e-4f

// ---------------------------------------------------------------------------
template <int LOGW, int DO_MSE, int DO_POOL>
__global__ __launch_bounds__(256, 6) void ssim_stream(
    const float* __restrict__ x1, const float* __restrict__ x2, GaussW gw,
    float* __restrict__ partials, float* __restrict__ msep,
    float* __restrict__ d1, float* __restrict__ d2)
{
  constexpr int W = 1 << LOGW;
  constexpr int Ho = W - 10;
  constexpr int CS = (Ho + 63) >> 6;   // col strips (64 out cols each)
  constexpr int RS = (Ho + 31) >> 5;   // row strips (32 out rows each)
  constexpr int PW = RS * CS;          // waves per plane
  constexpr int W2 = W >> 1;

  // [wave][slot][img][col] ; 76 cols (74 used) ; 7296 B per 4-wave block
  __shared__ float rowbuf[4][3][2][76];

  const int tid = threadIdx.x;
  const int wid = tid >> 6, lane = tid & 63;
  const int gwid = blockIdx.x * 4 + wid;
  const int plane = gwid / PW;
  const int rem = gwid - plane * PW;
  const int rsi = rem / CS;
  const int csi = rem - rsi * CS;

  const int gr0 = 32 * rsi;
  const int c0 = 64 * csi;
  const int gc = c0 + lane;
  int ROWS = Ho - gr0 + 10; if (ROWS > 42) ROWS = 42;

  const size_t pb = (size_t)plane * W * W;
  const float* q1 = x1 + pb + gc;
  const float* q2 = x2 + pb + gc;
  const bool cok = gc < W;
  const bool eok = (lane < 10) && (gc + 64 < W);

  float (*rb)[2][76] = rowbuf[wid];

  float mse_acc = 0.f, ssim_acc = 0.f, cs_acc = 0.f;

  // transposed-FIR accumulators: acc*[10] emits out row (rr-10)
  float acc0[11], acc1[11], acc2[11], acc3[11], acc4[11];
#pragma unroll
  for (int j = 0; j < 11; ++j) {
    acc0[j] = 0.f; acc1[j] = 0.f; acc2[j] = 0.f; acc3[j] = 0.f; acc4[j] = 0.f;
  }

#define LOADROW(R, V)                                                   \
  {                                                                     \
    V.x = 0.f; V.y = 0.f; V.z = 0.f; V.w = 0.f;                         \
    if ((R) < ROWS) {                                                   \
      size_t ro = (size_t)(gr0 + (R)) * W;                              \
      if (cok) { V.x = q1[ro]; V.y = q2[ro]; }                          \
      if (eok) { V.z = q1[ro + 64]; V.w = q2[ro + 64]; }                \
      if (DO_MSE && (R) < 32) {                                         \
        float d_ = V.x - V.y;                                           \
        mse_acc = fmaf(d_, d_, mse_acc);                                \
      }                                                                 \
    }                                                                   \
  }

#define WRITEROW(SLOT, V)                                               \
  {                                                                     \
    rb[SLOT][0][lane] = V.x;                                            \
    rb[SLOT][1][lane] = V.y;                                            \
    if (lane < 10) {                                                    \
      rb[SLOT][0][64 + lane] = V.z;                                     \
      rb[SLOT][1][64 + lane] = V.w;                                     \
    }                                                                   \
  }

  // prologue: row0 staged; rows 1,2 in register pipeline
  float4 vA, vB, vT;
  LOADROW(0, vT)
  WRITEROW(0, vT)
  LOADROW(1, vA)
  LOADROW(2, vB)

  int cur = 0;
  for (int rr = 0; rr < ROWS; ++rr) {
    int nxt = cur + 1; if (nxt == 3) nxt = 0;
    int prv = cur - 1; if (prv < 0) prv = 2;

    // wave fence: prior ds_writes (row rr into slot cur) visible to reads
    asm volatile("s_waitcnt lgkmcnt(0)" ::: "memory");
    __builtin_amdgcn_sched_barrier(0);

    // stage row rr+1 (loaded 2 iters ago) into slot nxt
    if (rr + 1 < ROWS) WRITEROW(nxt, vA)
    vA = vB;
    LOADROW(rr + 3, vB)

    // ---- H-pass: 11-tap window from slot cur, static offsets ----
    const float* r1 = &rb[cur][0][lane];
    const float* r2 = &rb[cur][1][lane];
    float s1 = 0.f, s2 = 0.f, s11 = 0.f, s22 = 0.f, s12 = 0.f;
#pragma unroll
    for (int k = 0; k < 11; ++k) {
      float av = r1[k], bv = r2[k], w = gw.g[k];
      float wa = w * av, wb = w * bv;
      s1 += wa; s2 += wb;
      s11 = fmaf(wa, av, s11);
      s22 = fmaf(wb, bv, s22);
      s12 = fmaf(wa, bv, s12);
    }

    // ---- V-pass: shift-accumulate (static indices) ----
#pragma unroll
    for (int j = 10; j >= 1; --j) {
      acc0[j] = fmaf(gw.g[j], s1, acc0[j - 1]);
      acc1[j] = fmaf(gw.g[j], s2, acc1[j - 1]);
      acc2[j] = fmaf(gw.g[j], s11, acc2[j - 1]);
      acc3[j] = fmaf(gw.g[j], s22, acc3[j - 1]);
      acc4[j] = fmaf(gw.g[j], s12, acc4[j - 1]);
    }
    acc0[0] = gw.g[0] * s1;
    acc1[0] = gw.g[0] * s2;
    acc2[0] = gw.g[0] * s11;
    acc3[0] = gw.g[0] * s22;
    acc4[0] = gw.g[0] * s12;

    // ---- emit SSIM/CS for out row (gr0 + rr - 10) ----
    if (rr >= 10 && gc < Ho) {
      float m1 = acc0[10], m2 = acc1[10];
      float m1sq = m1 * m1, m2sq = m2 * m2, m12 = m1 * m2;
      float v1 = 2.f * (acc4[10] - m12) + C2F;
      float v2 = (acc2[10] - m1sq) + (acc3[10] - m2sq) + C2F;
      float csv = v1 * __builtin_amdgcn_rcpf(v2);
      cs_acc += csv;
      ssim_acc += csv * (2.f * m12 + C1F) *
                  __builtin_amdgcn_rcpf(m1sq + m2sq + C1F);
    }

    // ---- fused 2x2 avgpool on raw rows (rr-1, rr) ----
    if (DO_POOL && (rr & 1) && rr < 32 && lane < 32) {
      float a00 = rb[prv][0][2 * lane], a01 = rb[prv][0][2 * lane + 1];
      float a10 = rb[cur][0][2 * lane], a11 = rb[cur][0][2 * lane + 1];
      float b00 = rb[prv][1][2 * lane], b01 = rb[prv][1][2 * lane + 1];
      float b10 = rb[cur][1][2 * lane], b11 = rb[cur][1][2 * lane + 1];
      int orow = 16 * rsi + (rr >> 1);
      size_t ob = (size_t)plane * W2 * W2 + (size_t)orow * W2 + (c0 >> 1) + lane;
      d1[ob] = 0.25f * ((a00 + a01) + (a10 + a11));
      d2[ob] = 0.25f * ((b00 + b01) + (b10 + b11));
    }

    cur = nxt;
  }
#undef LOADROW
#undef WRITEROW

  // ---- wave reduce + per-wave partial write ----
#pragma unroll
  for (int off = 32; off; off >>= 1) {
    ssim_acc += __shfl_down(ssim_acc, off);
    cs_acc += __shfl_down(cs_acc, off);
    if (DO_MSE) mse_acc += __shfl_down(mse_acc, off);
  }
  if (lane == 0) {
    partials[2 * gwid] = ssim_acc;
    partials[2 * gwid + 1] = cs_acc;
    if (DO_MSE) msep[gwid] = mse_acc;
  }
}

// ---------------------------------------------------------------------------
__global__ __launch_bounds__(256) void final_kernel(
    const float* __restrict__ ws, float* __restrict__ out)
{
  __shared__ double sred[2][4];
  __shared__ double fin[11];  // ssim[5], cs[5], mse
  const int tid = threadIdx.x;
  const int offs[5] = {P_L0, P_L1, P_L2, P_L3, P_L4};
  const int cnts[5] = {6144, 1536, 384, 96, 48};

  for (int l = 0; l < 5; ++l) {
    double s0 = 0.0, s1 = 0.0;
    for (int i = tid; i < cnts[l]; i += 256) {
      s0 += (double)ws[offs[l] + 2 * i];
      s1 += (double)ws[offs[l] + 2 * i + 1];
    }
#pragma unroll
    for (int off = 32; off; off >>= 1) {
      s0 += __shfl_down(s0, off);
      s1 += __shfl_down(s1, off);
    }
    if ((tid & 63) == 0) { sred[0][tid >> 6] = s0; sred[1][tid >> 6] = s1; }
    __syncthreads();
    if (tid == 0) {
      double aa = 0.0, bb = 0.0;
      for (int i = 0; i < 4; ++i) { aa += sred[0][i]; bb += sred[1][i]; }
      fin[l] = aa;
      fin[5 + l] = bb;
    }
    __syncthreads();
  }

  {
    double s0 = 0.0;
    for (int i = tid; i < 6144; i += 256) s0 += (double)ws[P_MSE + i];
#pragma unroll
    for (int off = 32; off; off >>= 1) s0 += __shfl_down(s0, off);
    if ((tid & 63) == 0) sred[0][tid >> 6] = s0;
    __syncthreads();
    if (tid == 0) {
      double aa = 0.0;
      for (int i = 0; i < 4; ++i) aa += sred[0][i];
      fin[10] = aa;
    }
    __syncthreads();
  }

  if (tid == 0) {
    const double wts[5] = {0.0448, 0.2856, 0.3001, 0.2363, 0.1333};
    const double dims[5] = {502.0, 246.0, 118.0, 54.0, 22.0};
    double mssim[5], mcs[5];
    for (int l = 0; l < 5; ++l) {
      double n = 48.0 * dims[l] * dims[l];
      mssim[l] = fin[l] / n;
      mcs[l] = fin[5 + l] / n;
    }
    // literal pytorch_msssim translation: prod(pow1[:-1] * pow2[-1])
    double p2last = pow(mssim[4], wts[4]);
    double prod = 1.0;
    for (int i = 0; i < 4; ++i) prod *= pow(mcs[i], wts[i]) * p2last;
    double msssim = prod;
    double mse = fin[10] / 12582912.0;
    out[0] = (float)(mse - msssim + 1.0);
    out[1] = (float)msssim;
  }
}

// ---------------------------------------------------------------------------
extern "C" void kernel_launch(void* const* d_in, const int* in_sizes, int n_in,
                              void* d_out, int out_size, void* d_ws, size_t ws_size,
                              hipStream_t stream)
{
  const float* rec = (const float*)d_in[0];   // reconst
  const float* orig = (const float*)d_in[1];  // original
  float* ws = (float*)d_ws;
  float* out = (float*)d_out;

  GaussW gw;
  {
    double g[11], s = 0.0;
    for (int i = 0; i < 11; ++i) {
      double x = (double)i - 5.0;
      g[i] = exp(-(x * x) / 4.5);
      s += g[i];
    }
    for (int i = 0; i < 11; ++i) gw.g[i] = (float)(g[i] / s);
  }

  // pyramid pointers
  float* A1 = ws + 0;
  float* A2 = ws + 3145728;
  float* A3 = ws + 3932160;
  float* A4 = ws + 4128768;
  float* B1 = ws + PYR2_OFF;
  float* B2 = ws + PYR2_OFF + 3145728;
  float* B3 = ws + PYR2_OFF + 3932160;
  float* B4 = ws + PYR2_OFF + 4128768;

  // waves per level: 48*RS*CS -> blocks = waves/4
  ssim_stream<9, 1, 1><<<dim3(1536), 256, 0, stream>>>(
      orig, rec, gw, ws + P_L0, ws + P_MSE, A1, B1);   // 16x8 strips
  ssim_stream<8, 0, 1><<<dim3(384), 256, 0, stream>>>(
      A1, B1, gw, ws + P_L1, nullptr, A2, B2);         // 8x4
  ssim_stream<7, 0, 1><<<dim3(96), 256, 0, stream>>>(
      A2, B2, gw, ws + P_L2, nullptr, A3, B3);         // 4x2
  ssim_stream<6, 0, 1><<<dim3(24), 256, 0, stream>>>(
      A3, B3, gw, ws + P_L3, nullptr, A4, B4);         // 2x1
  ssim_stream<5, 0, 0><<<dim3(12), 256, 0, stream>>>(
      A4, B4, gw, ws + P_L4, nullptr, nullptr, nullptr); // 1x1

  final_kernel<<<dim3(1), dim3(256), 0, stream>>>(ws, out);
}

// Round 7
// 210.970 us; speedup vs baseline: 2.4180x; 2.4180x over previous
//
#include <hip/hip_runtime.h>
#include <math.h>

// ---------------------------------------------------------------------------
// MS-SSIM + MSE loss, (16,3,512,512) f32, 5 pyramid levels.
// R7: wave-private column streaming (R6 structure) with the spill fixed.
//  - launch_bounds(256,4): 128-VGPR budget, no scratch.
//  - Row loop = 4 x (unroll 11): FIR-shift rotation is register RENAMING
//    (period 11), LDS ring has 11 slots so slot indices are compile-time.
//  - Per-row wave fence only (s_waitcnt lgkmcnt(0) + sched_barrier); no
//    __syncthreads in the loop. Global loads 2 rows ahead in registers.
// MSE (L0) + 2x2 avgpool fused. Per-wave partials, final 1-block f64 reduce.
// ---------------------------------------------------------------------------

#define NPLANES 48

struct GaussW { float g[11]; };

// ws float offsets: pyramids + per-WAVE partial areas
#define PYR2_OFF  4177920
#define P_L0      8355840   // 6144 pairs
#define P_L1      8368128   // 1536 pairs
#define P_L2      8371200   // 384 pairs
#define P_L3      8371968   // 96 pairs
#define P_L4      8372160   // 48 pairs
#define P_MSE     8372256   // 6144 singles

#define C1F 1.0e-4f
#define C2F 9.0e-4f

// ---------------------------------------------------------------------------
template <int LOGW, int DO_MSE, int DO_POOL>
__global__ __launch_bounds__(256, 4) void ssim_stream(
    const float* __restrict__ x1, const float* __restrict__ x2, GaussW gw,
    float* __restrict__ partials, float* __restrict__ msep,
    float* __restrict__ d1, float* __restrict__ d2)
{
  constexpr int W = 1 << LOGW;
  constexpr int Ho = W - 10;
  constexpr int CS = (Ho + 63) >> 6;   // col strips (64 out cols each)
  constexpr int RS = (Ho + 31) >> 5;   // row strips (32 out rows each)
  constexpr int PW = RS * CS;          // waves per plane
  constexpr int W2 = W >> 1;

  // [wave][slot][img][col]: 11-slot ring, static slot indices. 26752 B.
  __shared__ float rowbuf[4][11][2][76];

  const int tid = threadIdx.x;
  const int wid = tid >> 6, lane = tid & 63;
  const int gwid = blockIdx.x * 4 + wid;
  const int plane = gwid / PW;
  const int rem = gwid - plane * PW;
  const int rsi = rem / CS;
  const int csi = rem - rsi * CS;

  const int gr0 = 32 * rsi;
  const int c0 = 64 * csi;
  const int gc = c0 + lane;
  int ROWS = Ho - gr0 + 10; if (ROWS > 42) ROWS = 42;

  const size_t pb = (size_t)plane * W * W;
  const float* q1 = x1 + pb + gc;
  const float* q2 = x2 + pb + gc;
  const bool cok = gc < W;
  const bool eok = (lane < 10) && (gc + 64 < W);

  float (*rb)[2][76] = rowbuf[wid];

  float mse_acc = 0.f, ssim_acc = 0.f, cs_acc = 0.f;

  // transposed-FIR accumulators: acc*[10] emits out row (rr-10)
  float acc0[11], acc1[11], acc2[11], acc3[11], acc4[11];
#pragma unroll
  for (int j = 0; j < 11; ++j) {
    acc0[j] = 0.f; acc1[j] = 0.f; acc2[j] = 0.f; acc3[j] = 0.f; acc4[j] = 0.f;
  }

#define LOADROW(R, V)                                                   \
  {                                                                     \
    V.x = 0.f; V.y = 0.f; V.z = 0.f; V.w = 0.f;                         \
    if ((R) < ROWS) {                                                   \
      size_t ro = (size_t)(gr0 + (R)) * W;                              \
      if (cok) { V.x = q1[ro]; V.y = q2[ro]; }                          \
      if (eok) { V.z = q1[ro + 64]; V.w = q2[ro + 64]; }                \
      if (DO_MSE && (R) < 32) {                                         \
        float d_ = V.x - V.y;                                           \
        mse_acc = fmaf(d_, d_, mse_acc);                                \
      }                                                                 \
    }                                                                   \
  }

#define WRITEROW(SLOT, V)                                               \
  {                                                                     \
    rb[SLOT][0][lane] = V.x;                                            \
    rb[SLOT][1][lane] = V.y;                                            \
    if (lane < 10) {                                                    \
      rb[SLOT][0][64 + lane] = V.z;                                     \
      rb[SLOT][1][64 + lane] = V.w;                                     \
    }                                                                   \
  }

  // prologue: row0 staged in slot 0; rows 1,2 in register pipeline
  float4 vA, vB, vT;
  LOADROW(0, vT)
  WRITEROW(0, vT)
  LOADROW(1, vA)
  LOADROW(2, vB)

  for (int t = 0; t < 4; ++t) {
#pragma unroll
    for (int u = 0; u < 11; ++u) {
      const int rr = 11 * t + u;          // row in slot u (u == rr % 11)
      const int sW = (u + 1) % 11;        // slot for row rr+1 (static)
      const int sP = (u + 10) % 11;       // slot holding row rr-1 (static)

      // wave fence: prior ds_writes visible before this iteration's reads
      asm volatile("s_waitcnt lgkmcnt(0)" ::: "memory");
      __builtin_amdgcn_sched_barrier(0);

      // stage row rr+1 (loaded 2 iters ago); advance register pipeline
      if (rr + 1 < ROWS) WRITEROW(sW, vA)
      vA = vB;
      LOADROW(rr + 3, vB)

      // ---- H-pass: 11-tap window from slot u, static offsets ----
      const float* r1 = &rb[u][0][lane];
      const float* r2 = &rb[u][1][lane];
      float s1 = 0.f, s2 = 0.f, s11 = 0.f, s22 = 0.f, s12 = 0.f;
#pragma unroll
      for (int k = 0; k < 11; ++k) {
        float av = r1[k], bv = r2[k], w = gw.g[k];
        float wa = w * av, wb = w * bv;
        s1 += wa; s2 += wb;
        s11 = fmaf(wa, av, s11);
        s22 = fmaf(wb, bv, s22);
        s12 = fmaf(wa, bv, s12);
      }

      // ---- V-pass: shift-accumulate (rotation renamed over 11 iters) ----
#pragma unroll
      for (int j = 10; j >= 1; --j) {
        acc0[j] = fmaf(gw.g[j], s1, acc0[j - 1]);
        acc1[j] = fmaf(gw.g[j], s2, acc1[j - 1]);
        acc2[j] = fmaf(gw.g[j], s11, acc2[j - 1]);
        acc3[j] = fmaf(gw.g[j], s22, acc3[j - 1]);
        acc4[j] = fmaf(gw.g[j], s12, acc4[j - 1]);
      }
      acc0[0] = gw.g[0] * s1;
      acc1[0] = gw.g[0] * s2;
      acc2[0] = gw.g[0] * s11;
      acc3[0] = gw.g[0] * s22;
      acc4[0] = gw.g[0] * s12;

      // ---- emit SSIM/CS for out row (gr0 + rr - 10) ----
      if (rr >= 10 && rr < ROWS && gc < Ho) {
        float m1 = acc0[10], m2 = acc1[10];
        float m1sq = m1 * m1, m2sq = m2 * m2, m12 = m1 * m2;
        float v1 = 2.f * (acc4[10] - m12) + C2F;
        float v2 = (acc2[10] - m1sq) + (acc3[10] - m2sq) + C2F;
        float csv = v1 * __builtin_amdgcn_rcpf(v2);
        cs_acc += csv;
        ssim_acc += csv * (2.f * m12 + C1F) *
                    __builtin_amdgcn_rcpf(m1sq + m2sq + C1F);
      }

      // ---- fused 2x2 avgpool on raw rows (rr-1, rr) ----
      if (DO_POOL && (rr & 1) && rr < 32 && rr < ROWS && lane < 32) {
        float a00 = rb[sP][0][2 * lane], a01 = rb[sP][0][2 * lane + 1];
        float a10 = rb[u][0][2 * lane],  a11 = rb[u][0][2 * lane + 1];
        float b00 = rb[sP][1][2 * lane], b01 = rb[sP][1][2 * lane + 1];
        float b10 = rb[u][1][2 * lane],  b11 = rb[u][1][2 * lane + 1];
        int orow = 16 * rsi + (rr >> 1);
        size_t ob = (size_t)plane * W2 * W2 + (size_t)orow * W2 + (c0 >> 1) + lane;
        d1[ob] = 0.25f * ((a00 + a01) + (a10 + a11));
        d2[ob] = 0.25f * ((b00 + b01) + (b10 + b11));
      }
    }
  }
#undef LOADROW
#undef WRITEROW

  // ---- wave reduce + per-wave partial write ----
#pragma unroll
  for (int off = 32; off; off >>= 1) {
    ssim_acc += __shfl_down(ssim_acc, off);
    cs_acc += __shfl_down(cs_acc, off);
    if (DO_MSE) mse_acc += __shfl_down(mse_acc, off);
  }
  if (lane == 0) {
    partials[2 * gwid] = ssim_acc;
    partials[2 * gwid + 1] = cs_acc;
    if (DO_MSE) msep[gwid] = mse_acc;
  }
}

// ---------------------------------------------------------------------------
__global__ __launch_bounds__(256) void final_kernel(
    const float* __restrict__ ws, float* __restrict__ out)
{
  __shared__ double sred[2][4];
  __shared__ double fin[11];  // ssim[5], cs[5], mse
  const int tid = threadIdx.x;
  const int offs[5] = {P_L0, P_L1, P_L2, P_L3, P_L4};
  const int cnts[5] = {6144, 1536, 384, 96, 48};

  for (int l = 0; l < 5; ++l) {
    double s0 = 0.0, s1 = 0.0;
    for (int i = tid; i < cnts[l]; i += 256) {
      s0 += (double)ws[offs[l] + 2 * i];
      s1 += (double)ws[offs[l] + 2 * i + 1];
    }
#pragma unroll
    for (int off = 32; off; off >>= 1) {
      s0 += __shfl_down(s0, off);
      s1 += __shfl_down(s1, off);
    }
    if ((tid & 63) == 0) { sred[0][tid >> 6] = s0; sred[1][tid >> 6] = s1; }
    __syncthreads();
    if (tid == 0) {
      double aa = 0.0, bb = 0.0;
      for (int i = 0; i < 4; ++i) { aa += sred[0][i]; bb += sred[1][i]; }
      fin[l] = aa;
      fin[5 + l] = bb;
    }
    __syncthreads();
  }

  {
    double s0 = 0.0;
    for (int i = tid; i < 6144; i += 256) s0 += (double)ws[P_MSE + i];
#pragma unroll
    for (int off = 32; off; off >>= 1) s0 += __shfl_down(s0, off);
    if ((tid & 63) == 0) sred[0][tid >> 6] = s0;
    __syncthreads();
    if (tid == 0) {
      double aa = 0.0;
      for (int i = 0; i < 4; ++i) aa += sred[0][i];
      fin[10] = aa;
    }
    __syncthreads();
  }

  if (tid == 0) {
    const double wts[5] = {0.0448, 0.2856, 0.3001, 0.2363, 0.1333};
    const double dims[5] = {502.0, 246.0, 118.0, 54.0, 22.0};
    double mssim[5], mcs[5];
    for (int l = 0; l < 5; ++l) {
      double n = 48.0 * dims[l] * dims[l];
      mssim[l] = fin[l] / n;
      mcs[l] = fin[5 + l] / n;
    }
    // literal pytorch_msssim translation: prod(pow1[:-1] * pow2[-1])
    double p2last = pow(mssim[4], wts[4]);
    double prod = 1.0;
    for (int i = 0; i < 4; ++i) prod *= pow(mcs[i], wts[i]) * p2last;
    double msssim = prod;
    double mse = fin[10] / 12582912.0;
    out[0] = (float)(mse - msssim + 1.0);
    out[1] = (float)msssim;
  }
}

// ---------------------------------------------------------------------------
extern "C" void kernel_launch(void* const* d_in, const int* in_sizes, int n_in,
                              void* d_out, int out_size, void* d_ws, size_t ws_size,
                              hipStream_t stream)
{
  const float* rec = (const float*)d_in[0];   // reconst
  const float* orig = (const float*)d_in[1];  // original
  float* ws = (float*)d_ws;
  float* out = (float*)d_out;

  GaussW gw;
  {
    double g[11], s = 0.0;
    for (int i = 0; i < 11; ++i) {
      double x = (double)i - 5.0;
      g[i] = exp(-(x * x) / 4.5);
      s += g[i];
    }
    for (int i = 0; i < 11; ++i) gw.g[i] = (float)(g[i] / s);
  }

  // pyramid pointers
  float* A1 = ws + 0;
  float* A2 = ws + 3145728;
  float* A3 = ws + 3932160;
  float* A4 = ws + 4128768;
  float* B1 = ws + PYR2_OFF;
  float* B2 = ws + PYR2_OFF + 3145728;
  float* B3 = ws + PYR2_OFF + 3932160;
  float* B4 = ws + PYR2_OFF + 4128768;

  // waves per level: 48*RS*CS -> blocks = waves/4
  ssim_stream<9, 1, 1><<<dim3(1536), 256, 0, stream>>>(
      orig, rec, gw, ws + P_L0, ws + P_MSE, A1, B1);     // 16x8 strips
  ssim_stream<8, 0, 1><<<dim3(384), 256, 0, stream>>>(
      A1, B1, gw, ws + P_L1, nullptr, A2, B2);           // 8x4
  ssim_stream<7, 0, 1><<<dim3(96), 256, 0, stream>>>(
      A2, B2, gw, ws + P_L2, nullptr, A3, B3);           // 4x2
  ssim_stream<6, 0, 1><<<dim3(24), 256, 0, stream>>>(
      A3, B3, gw, ws + P_L3, nullptr, A4, B4);           // 2x1
  ssim_stream<5, 0, 0><<<dim3(12), 256, 0, stream>>>(
      A4, B4, gw, ws + P_L4, nullptr, nullptr, nullptr); // 1x1

  final_kernel<<<dim3(1), dim3(256), 0, stream>>>(ws, out);
}